// Round 1
// baseline (658.162 us; speedup 1.0000x reference)
//
#include <hip/hip_runtime.h>
#include <stdint.h>
#include <stddef.h>

// Problem constants (fixed by reference)
#define NB 32
#define NN 8192
#define NH 512
#define NE 10
#define HEPS 1e-5f
#define HSLOPE 0.2f

typedef short short8 __attribute__((ext_vector_type(8)));
typedef float f32x4 __attribute__((ext_vector_type(4)));

static __device__ __forceinline__ unsigned short f2bf(float f){
  unsigned u = __float_as_uint(f);
  u += 0x7FFFu + ((u >> 16) & 1u);   // RNE
  return (unsigned short)(u >> 16);
}
static __device__ __forceinline__ float bf2f(unsigned short h){
  return __uint_as_float(((unsigned)h) << 16);
}

// ---------------------------------------------------------------------------
// Prep: W2 [E][512][256] f32  ->  bf16, pre-swizzled K-chunk layout in ws.
// Per expert: 8 chunks (kc) of 64 k-rows; chunk = 2 sub-tiles (k 0..31,32..63);
// halfword index within sub-tile: ((col*32 + k&31) ^ ((col&7)<<3)).
// Swizzle matches the ds_read_b128 B-fragment pattern (bank-conflict-free) and
// lets the main kernel stage chunks with linear global_load_lds.
// ---------------------------------------------------------------------------
__global__ __launch_bounds__(256) void prep_w2(const float* __restrict__ W2,
                                               unsigned short* __restrict__ ws){
  int idx = blockIdx.x * 256 + threadIdx.x;      // 0 .. 10*512*256-1 (coalesced read)
  int col = idx & 255;
  int k   = (idx >> 8) & 511;
  int e   = idx >> 17;
  unsigned short v = f2bf(W2[idx]);
  int kc = k >> 6, sub = (k >> 5) & 1, kl = k & 31;
  ws[(e << 17) + (kc << 14) + (sub << 13) + (((col << 5) + kl) ^ ((col & 7) << 3))] = v;
}

// ---------------------------------------------------------------------------
// Fused kernel: one block = one batch b, 64 points.
//   Phase A : layer1 (fp32) -> LN1 stats -> lrelu -> bf16 A-tile in LDS (swizzled)
//   GEMM    : 64x256 = A(64x512,bf16) x W2(512x256,bf16), mfma 16x16x32,
//             BK=64 double-buffered chunks via global_load_lds
//   Epilog  : +b2 -> fp32 h2 in LDS -> LN2 -> lrelu -> layer3 dot (3 outs) -> out
// ---------------------------------------------------------------------------
template<bool PREP>
__global__ __launch_bounds__(256, 1) void fused_mlp(
  const float* __restrict__ points, const int* __restrict__ cats,
  const float* __restrict__ W1, const float* __restrict__ b1,
  const float* __restrict__ g1, const float* __restrict__ be1,
  const float* __restrict__ W2f, const float* __restrict__ b2,
  const float* __restrict__ g2, const float* __restrict__ be2,
  const float* __restrict__ W3, const float* __restrict__ b3,
  const unsigned short* __restrict__ W2s,
  float* __restrict__ out)
{
  __shared__ union SM {
    struct { unsigned short h1[64 * 512]; unsigned short Bs[2][16384]; } g; // 64K + 64K
    float h2[64 * 260];                                                     // 66.5K (post-GEMM overlay)
  } sm;

  const int t    = (int)threadIdx.x;
  const int lane = t & 63;
  const int w    = t >> 6;                 // wave id 0..3 (owns cols [64w,64w+64))
  const int bx   = (int)blockIdx.x;
  const int b    = bx >> 7;                // 128 tiles per batch
  const int n0   = (bx & 127) << 6;
  const int e    = cats[b];

  auto stage = [&](int buf, int kc){
    if constexpr (PREP){
      // linear 32KB copy: ws image is pre-swizzled
      const unsigned char* src = (const unsigned char*)(W2s + (e << 17) + (kc << 14));
      #pragma unroll
      for(int i = 0; i < 8; i++){
        int seg = w * 8 + i;               // 32 segs of 1KB across 4 waves
        __builtin_amdgcn_global_load_lds(
          (const __attribute__((address_space(1))) unsigned int*)(src + seg * 1024 + lane * 16),
          (__attribute__((address_space(3))) unsigned int*)(&sm.g.Bs[buf][seg * 512]),
          16, 0, 0);
      }
    } else {
      // fallback: stage from fp32 W2 with on-the-fly convert + swizzled 2B writes
      const float* src = W2f + ((e * 512 + kc * 64) << 8);
      #pragma unroll 4
      for(int i = 0; i < 64; i++){
        int idx = i * 256 + t;
        int col = idx & 255, kl = idx >> 8;         // coalesced over col
        sm.g.Bs[buf][((kl >> 5) << 13) + (((col << 5) + (kl & 31)) ^ ((col & 7) << 3))]
          = f2bf(src[(kl << 8) + col]);
      }
    }
  };

  // Prefetch chunk 0 now; it hides under Phase A. (LDS regions disjoint.)
  stage(0, 0);

  // ---------------- Phase A: layer1 + LN1 + lrelu -> bf16 LDS ----------------
  {
    const int p = t >> 2, q = t & 3;       // 4 threads per point, same wave
    const float* pp = points + (size_t)(b * NN + n0 + p) * 3;
    const float p0 = pp[0], p1 = pp[1], p2 = pp[2];
    const float* w1a = W1 + e * 3 * NH;
    const float* w1b = w1a + NH;
    const float* w1c = w1b + NH;
    const float* b1e = b1 + e * NH;
    float sum = 0.f, ssq = 0.f;
    #pragma unroll
    for(int j = 0; j < 16; j++){
      int c0 = q * 128 + j * 8;
      f32x4 a0 = *(const f32x4*)(w1a + c0), a1 = *(const f32x4*)(w1a + c0 + 4);
      f32x4 u0 = *(const f32x4*)(w1b + c0), u1 = *(const f32x4*)(w1b + c0 + 4);
      f32x4 d0 = *(const f32x4*)(w1c + c0), d1 = *(const f32x4*)(w1c + c0 + 4);
      f32x4 e0 = *(const f32x4*)(b1e + c0), e1 = *(const f32x4*)(b1e + c0 + 4);
      short8 pk;
      #pragma unroll
      for(int i = 0; i < 4; i++){
        float h = fmaf(p0, a0[i], fmaf(p1, u0[i], fmaf(p2, d0[i], e0[i])));
        sum += h; ssq = fmaf(h, h, ssq);
        pk[i] = (short)f2bf(h);
        float h2v = fmaf(p0, a1[i], fmaf(p1, u1[i], fmaf(p2, d1[i], e1[i])));
        sum += h2v; ssq = fmaf(h2v, h2v, ssq);
        pk[4 + i] = (short)f2bf(h2v);
      }
      *(short8*)(sm.g.h1 + (((p << 9) + c0) ^ ((p & 7) << 3))) = pk;  // swizzled
    }
    sum += __shfl_xor(sum, 1); sum += __shfl_xor(sum, 2);
    ssq += __shfl_xor(ssq, 1); ssq += __shfl_xor(ssq, 2);
    float mu = sum * (1.f / NH);
    float rs = rsqrtf(fmaf(-mu, mu, ssq * (1.f / NH)) + HEPS);
    const float* g1e  = g1  + e * NH;
    const float* be1e = be1 + e * NH;
    #pragma unroll
    for(int j = 0; j < 16; j++){
      int c0 = q * 128 + j * 8;
      int hw = ((p << 9) + c0) ^ ((p & 7) << 3);
      short8 v = *(short8*)(sm.g.h1 + hw);           // own data, same thread: no barrier
      f32x4 gg0 = *(const f32x4*)(g1e + c0),  gg1 = *(const f32x4*)(g1e + c0 + 4);
      f32x4 ee0 = *(const f32x4*)(be1e + c0), ee1 = *(const f32x4*)(be1e + c0 + 4);
      short8 pk;
      #pragma unroll
      for(int i = 0; i < 8; i++){
        float x = bf2f((unsigned short)v[i]);
        float gv = (i < 4) ? gg0[i] : gg1[i - 4];
        float bv = (i < 4) ? ee0[i] : ee1[i - 4];
        x = (x - mu) * rs;
        x = fmaf(x, gv, bv);
        x = (x >= 0.f) ? x : HSLOPE * x;
        pk[i] = (short)f2bf(x);
      }
      *(short8*)(sm.g.h1 + hw) = pk;
    }
  }
  __syncthreads();   // h1 visible to all; also drains chunk-0 staging (vmcnt/lgkm)

  // ---------------- GEMM: 8 chunks of BK=64, double-buffered ----------------
  f32x4 acc[4][4];
  #pragma unroll
  for(int m = 0; m < 4; m++)
    #pragma unroll
    for(int n = 0; n < 4; n++){ f32x4 z = {0.f,0.f,0.f,0.f}; acc[m][n] = z; }

  const int krow  = (lane >> 4) << 3;      // k-offset of this lane's 8 elems
  const int arow0 = lane & 15;
  int cur = 0;
  #pragma unroll 1
  for(int kc = 0; kc < 8; kc++){
    if(kc < 7) stage(cur ^ 1, kc + 1);
    const unsigned short* Bsp = sm.g.Bs[cur];
    #pragma unroll
    for(int sub = 0; sub < 2; sub++){
      short8 af[4], bfr[4];
      #pragma unroll
      for(int m = 0; m < 4; m++){
        int row = m * 16 + arow0;
        int hw = (((row << 9) + (kc << 6) + (sub << 5) + krow)) ^ ((row & 7) << 3);
        af[m] = *(const short8*)(sm.g.h1 + hw);
      }
      #pragma unroll
      for(int n = 0; n < 4; n++){
        int col = (w << 6) + n * 16 + arow0;
        int hw = (sub << 13) + (((col << 5) + krow) ^ ((col & 7) << 3));
        bfr[n] = *(const short8*)(Bsp + hw);
      }
      #pragma unroll
      for(int m = 0; m < 4; m++)
        #pragma unroll
        for(int n = 0; n < 4; n++)
          acc[m][n] = __builtin_amdgcn_mfma_f32_16x16x32_bf16(af[m], bfr[n], acc[m][n], 0, 0, 0);
    }
    __syncthreads();   // prefetch arrived + all waves done with 'cur' before overwrite
    cur ^= 1;
  }

  // ---------------- Epilogue: +b2 -> fp32 h2 (overlay) ----------------
  {
    const float* b2e = b2 + e * 256;
    #pragma unroll
    for(int n = 0; n < 4; n++){
      int col = (w << 6) + n * 16 + (lane & 15);
      float bc = b2e[col];
      #pragma unroll
      for(int m = 0; m < 4; m++){
        int row0 = m * 16 + ((lane >> 4) << 2);     // C/D layout: row=(l>>4)*4+r, col=l&15
        #pragma unroll
        for(int r = 0; r < 4; r++)
          sm.h2[(row0 + r) * 260 + col] = acc[m][n][r] + bc;
      }
    }
  }
  __syncthreads();

  // ---------------- LN2 + lrelu + layer3 ----------------
  {
    const int p = t >> 2, q = t & 3;
    const float* hrow = sm.h2 + p * 260 + q * 64;
    float s = 0.f, sq = 0.f;
    #pragma unroll
    for(int j = 0; j < 16; j++){
      f32x4 v = *(const f32x4*)(hrow + j * 4);
      #pragma unroll
      for(int i = 0; i < 4; i++){ s += v[i]; sq = fmaf(v[i], v[i], sq); }
    }
    s  += __shfl_xor(s, 1);  s  += __shfl_xor(s, 2);
    sq += __shfl_xor(sq, 1); sq += __shfl_xor(sq, 2);
    float mu = s * (1.f / 256.f);
    float rs = rsqrtf(fmaf(-mu, mu, sq * (1.f / 256.f)) + HEPS);
    const float* g2e  = g2  + e * 256 + q * 64;
    const float* be2e = be2 + e * 256 + q * 64;
    const float* w3e  = W3 + (e * 256 + q * 64) * 3;
    float o0 = 0.f, o1 = 0.f, o2 = 0.f;
    #pragma unroll 4
    for(int j = 0; j < 64; j++){
      float x = hrow[j];
      x = (x - mu) * rs;
      x = fmaf(x, g2e[j], be2e[j]);
      x = (x >= 0.f) ? x : HSLOPE * x;
      o0 = fmaf(x, w3e[j * 3 + 0], o0);
      o1 = fmaf(x, w3e[j * 3 + 1], o1);
      o2 = fmaf(x, w3e[j * 3 + 2], o2);
    }
    o0 += __shfl_xor(o0, 1); o0 += __shfl_xor(o0, 2);
    o1 += __shfl_xor(o1, 1); o1 += __shfl_xor(o1, 2);
    o2 += __shfl_xor(o2, 1); o2 += __shfl_xor(o2, 2);
    if(q == 0){
      float* op = out + (size_t)(b * NN + n0 + p) * 3;
      op[0] = o0 + b3[e * 3 + 0];
      op[1] = o1 + b3[e * 3 + 1];
      op[2] = o2 + b3[e * 3 + 2];
    }
  }
}

extern "C" void kernel_launch(void* const* d_in, const int* in_sizes, int n_in,
                              void* d_out, int out_size, void* d_ws, size_t ws_size,
                              hipStream_t stream) {
  const float* points = (const float*)d_in[0];
  const int*   cats   = (const int*)d_in[1];
  const float* W1  = (const float*)d_in[2];
  const float* b1  = (const float*)d_in[3];
  const float* g1  = (const float*)d_in[4];
  const float* be1 = (const float*)d_in[5];
  const float* W2  = (const float*)d_in[6];
  const float* b2  = (const float*)d_in[7];
  const float* g2  = (const float*)d_in[8];
  const float* be2 = (const float*)d_in[9];
  const float* W3  = (const float*)d_in[10];
  const float* b3  = (const float*)d_in[11];
  float* out = (float*)d_out;

  const size_t ws_needed = (size_t)NE * 512 * 256 * 2;   // 2.62 MB bf16 W2 image
  if (ws_size >= ws_needed) {
    unsigned short* ws = (unsigned short*)d_ws;
    prep_w2<<<dim3((NE * 512 * 256) / 256), dim3(256), 0, stream>>>(W2, ws);
    fused_mlp<true><<<dim3(NB * (NN / 64)), dim3(256), 0, stream>>>(
        points, cats, W1, b1, g1, be1, W2, b2, g2, be2, W3, b3, ws, out);
  } else {
    fused_mlp<false><<<dim3(NB * (NN / 64)), dim3(256), 0, stream>>>(
        points, cats, W1, b1, g1, be1, W2, b2, g2, be2, W3, b3, nullptr, out);
  }
}

// Round 2
// 552.705 us; speedup vs baseline: 1.1908x; 1.1908x over previous
//
#include <hip/hip_runtime.h>
#include <stdint.h>
#include <stddef.h>

// Problem constants (fixed by reference)
#define NB 32
#define NN 8192
#define NH 512
#define NE 10
#define HEPS 1e-5f
#define HSLOPE 0.2f

typedef short short8 __attribute__((ext_vector_type(8)));
typedef float f32x4 __attribute__((ext_vector_type(4)));

static __device__ __forceinline__ unsigned short f2bf(float f){
  unsigned u = __float_as_uint(f);
  u += 0x7FFFu + ((u >> 16) & 1u);   // RNE
  return (unsigned short)(u >> 16);
}
static __device__ __forceinline__ float bf2f(unsigned short h){
  return __uint_as_float(((unsigned)h) << 16);
}

// ---------------------------------------------------------------------------
// Prep: W2 [E][512][256] f32 -> bf16 k-major fragment image in ws.
// Layout: [e][kc(8)][sub(2)][col(256)][kslot(4)][kk(8)] halfwords, so a wave's
// B-fragment (col = n*16 + lane&15, k = kc*64+sub*32+(lane>>4)*8+kk) is ONE
// fully-coalesced global_load_dwordx4: 64 lanes x 16B = contiguous 1KB.
// ---------------------------------------------------------------------------
__global__ __launch_bounds__(256) void prep_w2(const float* __restrict__ W2,
                                               unsigned short* __restrict__ ws){
  int idx = blockIdx.x * 256 + threadIdx.x;   // e*131072 + k*256 + col (coalesced read)
  int col = idx & 255;
  int k   = (idx >> 8) & 511;
  int e   = idx >> 17;
  int kc = k >> 6, sub = (k >> 5) & 1, kslot = (k >> 3) & 3, kk = k & 7;
  ws[(((size_t)(e * 8 + kc) * 2 + sub) << 13) + (col << 5) + (kslot << 3) + kk]
      = f2bf(W2[idx]);
}

// ---------------------------------------------------------------------------
// Fused kernel: one block = one batch b, 64 points, 4 waves.
//   Phase A : layer1 fp32 (h in regs, bf16-packed) -> LN1 -> lrelu -> bf16 LDS
//   GEMM    : 64x256 = A(64x512 LDS) x W2(512x256, direct L2->reg loads),
//             mfma 16x16x32, K-loop is BARRIER-FREE, 2-deep B prefetch
//   Epilog  : +b2 -> fp32 h2 LDS overlay (bank-conflict-free 292/72 strides)
//             -> LN2 -> lrelu -> layer3 dot -> out
// LDS = max(64KB h1, 74.75KB h2) -> 2 blocks/CU.
// ---------------------------------------------------------------------------
template<bool PREP>
__global__ __launch_bounds__(256, 2) void fused_mlp(
  const float* __restrict__ points, const int* __restrict__ cats,
  const float* __restrict__ W1, const float* __restrict__ b1,
  const float* __restrict__ g1, const float* __restrict__ be1,
  const float* __restrict__ W2f, const float* __restrict__ b2,
  const float* __restrict__ g2, const float* __restrict__ be2,
  const float* __restrict__ W3, const float* __restrict__ b3,
  const unsigned short* __restrict__ W2s,
  float* __restrict__ out)
{
  __shared__ union SM {
    unsigned short h1[64 * 512];   // 64KB bf16 A-tile (XOR-swizzled rows)
    float h2[64 * 292];            // 74.75KB fp32 post-GEMM overlay
  } sm;

  const int t    = (int)threadIdx.x;
  const int lane = t & 63;
  const int w    = t >> 6;                 // wave id 0..3 (owns cols [64w,64w+64))
  const int bx   = (int)blockIdx.x;
  const int b    = bx >> 7;                // 128 tiles per batch
  const int n0   = (bx & 127) << 6;
  const int e    = cats[b];

  // --- B-fragment loader: 8 frags (2 sub x 4 n) for one K-chunk, to regs ---
  const int bcol  = w * 64 + (lane & 15);  // + n*16
  const int kslot = lane >> 4;
  auto loadB = [&](short8* dst, int kc){
    if(kc >= 8) return;
    #pragma unroll
    for(int sub = 0; sub < 2; sub++){
      #pragma unroll
      for(int n = 0; n < 4; n++){
        if constexpr (PREP){
          const unsigned short* p = W2s + (((size_t)(e * 8 + kc) * 2 + sub) << 13)
                                  + (((bcol + n * 16) << 5) + (kslot << 3));
          dst[sub * 4 + n] = *(const short8*)p;
        } else {
          const float* p = W2f + (((size_t)e * 512 + kc * 64 + sub * 32 + kslot * 8) << 8)
                         + (bcol + n * 16);
          short8 v;
          #pragma unroll
          for(int kk = 0; kk < 8; kk++) v[kk] = (short)f2bf(p[(size_t)kk << 8]);
          dst[sub * 4 + n] = v;
        }
      }
    }
  };

  short8 bA[8], bB[8];
  loadB(bA, 0);    // prefetch chunk 0; hides under Phase A

  // ---------------- Phase A: layer1 + LN1 + lrelu -> bf16 LDS ----------------
  {
    const int p = t >> 2, q = t & 3;       // 4 threads per point (same wave)
    const float* pp = points + (size_t)(b * NN + n0 + p) * 3;
    const float p0 = pp[0], p1 = pp[1], p2 = pp[2];
    const float* w1a = W1 + (size_t)e * 3 * NH;
    const float* w1b = w1a + NH;
    const float* w1c = w1b + NH;
    const float* b1e = b1 + (size_t)e * NH;
    short8 hr[16];                          // pre-LN h, bf16-packed (64 VGPR)
    float sum = 0.f, ssq = 0.f;
    #pragma unroll
    for(int j = 0; j < 16; j++){
      int c0 = q * 128 + j * 8;
      f32x4 a0 = *(const f32x4*)(w1a + c0), a1 = *(const f32x4*)(w1a + c0 + 4);
      f32x4 u0 = *(const f32x4*)(w1b + c0), u1 = *(const f32x4*)(w1b + c0 + 4);
      f32x4 d0 = *(const f32x4*)(w1c + c0), d1 = *(const f32x4*)(w1c + c0 + 4);
      f32x4 e0 = *(const f32x4*)(b1e + c0), e1 = *(const f32x4*)(b1e + c0 + 4);
      short8 pk;
      #pragma unroll
      for(int i = 0; i < 4; i++){
        float h = fmaf(p0, a0[i], fmaf(p1, u0[i], fmaf(p2, d0[i], e0[i])));
        sum += h; ssq = fmaf(h, h, ssq);
        pk[i] = (short)f2bf(h);
        float h2v = fmaf(p0, a1[i], fmaf(p1, u1[i], fmaf(p2, d1[i], e1[i])));
        sum += h2v; ssq = fmaf(h2v, h2v, ssq);
        pk[4 + i] = (short)f2bf(h2v);
      }
      hr[j] = pk;
    }
    sum += __shfl_xor(sum, 1); sum += __shfl_xor(sum, 2);
    ssq += __shfl_xor(ssq, 1); ssq += __shfl_xor(ssq, 2);
    float mu = sum * (1.f / NH);
    float rs = rsqrtf(fmaf(-mu, mu, ssq * (1.f / NH)) + HEPS);
    const float* g1e  = g1  + (size_t)e * NH;
    const float* be1e = be1 + (size_t)e * NH;
    #pragma unroll
    for(int j = 0; j < 16; j++){
      int c0 = q * 128 + j * 8;
      f32x4 gg0 = *(const f32x4*)(g1e + c0),  gg1 = *(const f32x4*)(g1e + c0 + 4);
      f32x4 ee0 = *(const f32x4*)(be1e + c0), ee1 = *(const f32x4*)(be1e + c0 + 4);
      short8 v = hr[j], pk;
      #pragma unroll
      for(int i = 0; i < 8; i++){
        float x = bf2f((unsigned short)v[i]);
        float gv = (i < 4) ? gg0[i] : gg1[i - 4];
        float bv = (i < 4) ? ee0[i] : ee1[i - 4];
        x = (x - mu) * rs;
        x = fmaf(x, gv, bv);
        x = (x >= 0.f) ? x : HSLOPE * x;
        pk[i] = (short)f2bf(x);
      }
      // row-XOR swizzle: bank-conflict-free for both write and GEMM A-reads
      *(short8*)(sm.h1 + (((p << 9) + c0) ^ ((p & 7) << 3))) = pk;
    }
  }
  __syncthreads();   // h1 visible to all waves; ONLY barrier before epilogue

  // ---------------- GEMM: barrier-free K-loop, 2-deep B prefetch ----------------
  f32x4 acc[4][4];
  #pragma unroll
  for(int m = 0; m < 4; m++)
    #pragma unroll
    for(int n = 0; n < 4; n++){ f32x4 z = {0.f,0.f,0.f,0.f}; acc[m][n] = z; }

  const int krow  = (lane >> 4) << 3;
  const int arow0 = lane & 15;
  auto compute = [&](int kc, short8* bf){
    #pragma unroll
    for(int sub = 0; sub < 2; sub++){
      short8 af[4];
      #pragma unroll
      for(int m = 0; m < 4; m++){
        int row = m * 16 + arow0;
        int hw = ((row << 9) + (kc << 6) + (sub << 5) + krow) ^ ((row & 7) << 3);
        af[m] = *(const short8*)(sm.h1 + hw);
      }
      #pragma unroll
      for(int m = 0; m < 4; m++)
        #pragma unroll
        for(int n = 0; n < 4; n++)
          acc[m][n] = __builtin_amdgcn_mfma_f32_16x16x32_bf16(af[m], bf[sub * 4 + n], acc[m][n], 0, 0, 0);
    }
  };

  #pragma unroll
  for(int kc2 = 0; kc2 < 4; kc2++){
    loadB(bB, kc2 * 2 + 1);
    compute(kc2 * 2, bA);
    loadB(bA, kc2 * 2 + 2);
    compute(kc2 * 2 + 1, bB);
  }

  __syncthreads();   // all waves done reading h1 before h2 overlay

  // ---------------- Epilogue: +b2 -> fp32 h2 overlay ----------------
  // h2 word addr = p*292 + (c>>6)*72 + (c&63): 292%32=4, 72%32=8 ->
  // every consecutive 8-lane group hits 8 distinct 4-bank slots (conflict-free).
  {
    const float* b2e = b2 + e * 256;
    #pragma unroll
    for(int n = 0; n < 4; n++){
      int coll = n * 16 + (lane & 15);
      float bc = b2e[w * 64 + coll];
      #pragma unroll
      for(int m = 0; m < 4; m++){
        int row0 = m * 16 + ((lane >> 4) << 2);   // C/D: col=lane&15, row=(lane>>4)*4+r
        #pragma unroll
        for(int r = 0; r < 4; r++)
          sm.h2[(row0 + r) * 292 + w * 72 + coll] = acc[m][n][r] + bc;
      }
    }
  }
  __syncthreads();

  // ---------------- LN2 + lrelu + layer3 ----------------
  {
    const int p = t >> 2, q = t & 3;
    const float* hrow = sm.h2 + p * 292 + q * 72;   // thread q owns cols [64q,64q+64)
    float s = 0.f, sq = 0.f;
    #pragma unroll
    for(int j = 0; j < 16; j++){
      f32x4 v = *(const f32x4*)(hrow + j * 4);
      #pragma unroll
      for(int i = 0; i < 4; i++){ s += v[i]; sq = fmaf(v[i], v[i], sq); }
    }
    s  += __shfl_xor(s, 1);  s  += __shfl_xor(s, 2);
    sq += __shfl_xor(sq, 1); sq += __shfl_xor(sq, 2);
    float mu = s * (1.f / 256.f);
    float rs = rsqrtf(fmaf(-mu, mu, sq * (1.f / 256.f)) + HEPS);
    const float* g2e  = g2  + (size_t)e * 256 + q * 64;
    const float* be2e = be2 + (size_t)e * 256 + q * 64;
    const float* w3e  = W3 + ((size_t)e * 256 + q * 64) * 3;
    float o0 = 0.f, o1 = 0.f, o2 = 0.f;
    #pragma unroll 4
    for(int j = 0; j < 64; j++){
      float x = hrow[j];
      x = (x - mu) * rs;
      x = fmaf(x, g2e[j], be2e[j]);
      x = (x >= 0.f) ? x : HSLOPE * x;
      o0 = fmaf(x, w3e[j * 3 + 0], o0);
      o1 = fmaf(x, w3e[j * 3 + 1], o1);
      o2 = fmaf(x, w3e[j * 3 + 2], o2);
    }
    o0 += __shfl_xor(o0, 1); o0 += __shfl_xor(o0, 2);
    o1 += __shfl_xor(o1, 1); o1 += __shfl_xor(o1, 2);
    o2 += __shfl_xor(o2, 1); o2 += __shfl_xor(o2, 2);
    if(q == 0){
      float* op = out + (size_t)(b * NN + n0 + p) * 3;
      op[0] = o0 + b3[e * 3 + 0];
      op[1] = o1 + b3[e * 3 + 1];
      op[2] = o2 + b3[e * 3 + 2];
    }
  }
}

extern "C" void kernel_launch(void* const* d_in, const int* in_sizes, int n_in,
                              void* d_out, int out_size, void* d_ws, size_t ws_size,
                              hipStream_t stream) {
  const float* points = (const float*)d_in[0];
  const int*   cats   = (const int*)d_in[1];
  const float* W1  = (const float*)d_in[2];
  const float* b1  = (const float*)d_in[3];
  const float* g1  = (const float*)d_in[4];
  const float* be1 = (const float*)d_in[5];
  const float* W2  = (const float*)d_in[6];
  const float* b2  = (const float*)d_in[7];
  const float* g2  = (const float*)d_in[8];
  const float* be2 = (const float*)d_in[9];
  const float* W3  = (const float*)d_in[10];
  const float* b3  = (const float*)d_in[11];
  float* out = (float*)d_out;

  const size_t ws_needed = (size_t)NE * 512 * 256 * 2;   // 2.62 MB bf16 W2 image
  if (ws_size >= ws_needed) {
    unsigned short* ws = (unsigned short*)d_ws;
    prep_w2<<<dim3((NE * 512 * 256) / 256), dim3(256), 0, stream>>>(W2, ws);
    fused_mlp<true><<<dim3(NB * (NN / 64)), dim3(256), 0, stream>>>(
        points, cats, W1, b1, g1, be1, W2, b2, g2, be2, W3, b3, ws, out);
  } else {
    fused_mlp<false><<<dim3(NB * (NN / 64)), dim3(256), 0, stream>>>(
        points, cats, W1, b1, g1, be1, W2, b2, g2, be2, W3, b3, nullptr, out);
  }
}